// Round 18
// baseline (111.728 us; speedup 1.0000x reference)
//
#include <hip/hip_runtime.h>
#include <hip/hip_bf16.h>

// Problem constants: B=2, S=2048, D=1024, H=16, dk=64
#define S_LEN 2048
#define S_PAD 2112
#define D_DIM 1024
#define N_HEADS 16
#define M_ROWS 4096  // B*S

typedef __bf16 bf16x8 __attribute__((ext_vector_type(8)));
typedef float f32x4 __attribute__((ext_vector_type(4)));
typedef float f32x16 __attribute__((ext_vector_type(16)));
typedef unsigned short ushortx8 __attribute__((ext_vector_type(8)));
typedef unsigned int uintx4 __attribute__((ext_vector_type(4)));

__device__ __forceinline__ unsigned short f2bf(float f) {
  unsigned int u = __builtin_bit_cast(unsigned int, f);
  u += 0x7fffu + ((u >> 16) & 1u);   // RNE
  return (unsigned short)(u >> 16);
}

// v_cvt_pk_bf16_f32: packs 2 f32 -> u32 (lo|hi<<16), RNE. No builtin on gfx950.
__device__ __forceinline__ unsigned int cvtpk(float lo, float hi) {
  unsigned int r;
  asm("v_cvt_pk_bf16_f32 %0, %1, %2" : "=v"(r) : "v"(lo), "v"(hi));
  return r;
}

// v_permlane32_swap_b32 a, b: a.lanes[32:63] <-> b.lanes[0:31]
__device__ __forceinline__ void pl32swap(unsigned int& a, unsigned int& b) {
  asm("v_permlane32_swap_b32 %0, %1" : "+v"(a), "+v"(b));
}

__device__ __forceinline__ bf16x8 load8(const unsigned short* p) {
  return __builtin_bit_cast(bf16x8, *(const ushortx8*)p);
}

__device__ __forceinline__ void gload16(const unsigned short* g, unsigned short* l) {
  __builtin_amdgcn_global_load_lds((const __attribute__((address_space(1))) void*)g,
                                   (__attribute__((address_space(3))) void*)l,
                                   16, 0, 0);
}

// ---------------- fp32 -> bf16 convert (fused: x + 4 weights) ----------------
__global__ void cvt5_kernel(const float* __restrict__ s0, const float* __restrict__ s1,
                            const float* __restrict__ s2, const float* __restrict__ s3,
                            const float* __restrict__ s4,
                            unsigned short* __restrict__ d0, unsigned short* __restrict__ d1,
                            unsigned short* __restrict__ d2, unsigned short* __restrict__ d3,
                            unsigned short* __restrict__ d4,
                            int n4x, int n4w) {
  const int y = blockIdx.y;
  const float* s = (y == 0) ? s0 : (y == 1) ? s1 : (y == 2) ? s2 : (y == 3) ? s3 : s4;
  unsigned short* d = (y == 0) ? d0 : (y == 1) ? d1 : (y == 2) ? d2 : (y == 3) ? d3 : d4;
  const int n4 = (y == 0) ? n4x : n4w;
  int i = blockIdx.x * blockDim.x + threadIdx.x;
  if (i < n4) {
    float4 f = ((const float4*)s)[i];
    unsigned int u0 = cvtpk(f.x, f.y), u1 = cvtpk(f.z, f.w);
    unsigned long long packed = (unsigned long long)u0 | ((unsigned long long)u1 << 32);
    ((unsigned long long*)d)[i] = packed;
  }
}

// ---------------- bf16 GEMM: C = A[M,K] * B[N,K]^T, tile 128M x 64N ----------
// mode 0: fp32 row-major [M][N]; mode 1: bf16 [B,H,S,64] (Q pre-scaled);
// mode 2: bf16 [B,H,64,S_PAD] (V^T).
// Tile shrunk 128x128 -> 128x64 for residency: LDS 24KB, ~60 VGPR -> 6
// blocks/CU for QKV (1536 blocks; was 3/CU and 56% all-pipes-idle in R17).
// XCD-affinity (requires gridDim == (16,32,z)): XCD k owns the (n-half k&1,
// m-quad k>>1) slab, z slowest -> per-(XCD,z) active set = A-slab 2MB +
// B-half 1MB, L2-resident.
__global__ __launch_bounds__(256) void gemm_bt(
    const unsigned short* __restrict__ A,
    const unsigned short* __restrict__ B0,
    const unsigned short* __restrict__ B1,
    const unsigned short* __restrict__ B2,
    void* __restrict__ C0, void* __restrict__ C1, void* __restrict__ C2,
    int M, int N, int K, int modesel)
{
  __shared__ __align__(16) unsigned short At[128 * 64];   // 16KB
  __shared__ __align__(16) unsigned short Bt[64 * 64];    // 8KB

  // XCD remap: bid%8 = XCD; within XCD, x fastest (A-panel reuse), z slowest.
  const int bid = blockIdx.x + 16 * (blockIdx.y + 32 * blockIdx.z);
  const int k8 = bid & 7, t = bid >> 3;
  const int bxi = (k8 & 1) * 8 + (t & 7);           // 16 n-tiles of 64
  const int byi = (k8 >> 1) * 8 + ((t >> 3) & 7);   // 32 m-tiles of 128
  const int z   = t >> 6;                           // 0..2 (QKV) / 0 (outproj)

  const unsigned short* Bp = (z == 0) ? B0 : (z == 1) ? B1 : B2;
  void* Cp = (z == 0) ? C0 : (z == 1) ? C1 : C2;
  const int mode = (modesel == 0) ? 0 : ((z == 2) ? 2 : 1);
  const float escale = (modesel == 1 && z == 0) ? 0.180336879f : 1.0f;

  const int tid = threadIdx.x;
  const int lane = tid & 63, wave = tid >> 6;
  const int bm = byi * 128, bn = bxi * 64;
  const int wr = wave >> 1, wc = wave & 1;          // 2x2 waves over 128x64
  const int cl = lane & 15, g = lane >> 4;
  const int ci = lane >> 3, si = lane & 7;
  const int sg = si ^ (ci & 7);

  f32x4 acc[4][2] = {};

  for (int kb = 0; kb < K; kb += 64) {
    __syncthreads();
#pragma unroll
    for (int cc = 0; cc < 4; ++cc) {                // A: 16 chunks of 512
      int chunk = wave * 4 + cc;
      int row = chunk * 8 + ci;
      gload16(A + (size_t)(bm + row) * K + kb + sg * 8, &At[chunk * 512]);
    }
#pragma unroll
    for (int cc = 0; cc < 2; ++cc) {                // B: 8 chunks of 512
      int chunk = wave * 2 + cc;
      int row = chunk * 8 + ci;
      gload16(Bp + (size_t)(bn + row) * K + kb + sg * 8, &Bt[chunk * 512]);
    }
    __syncthreads();
#pragma unroll
    for (int kc = 0; kc < 2; ++kc) {
      bf16x8 af[4], bfr[2];
#pragma unroll
      for (int mi = 0; mi < 4; ++mi) {
        int row = wr * 64 + mi * 16 + cl;
        int slot = (kc * 4 + g) ^ (row & 7);
        af[mi] = load8(&At[row * 64 + slot * 8]);
      }
#pragma unroll
      for (int ni = 0; ni < 2; ++ni) {
        int row = wc * 32 + ni * 16 + cl;
        int slot = (kc * 4 + g) ^ (row & 7);
        bfr[ni] = load8(&Bt[row * 64 + slot * 8]);
      }
#pragma unroll
      for (int mi = 0; mi < 4; ++mi)
#pragma unroll
        for (int ni = 0; ni < 2; ++ni)
          acc[mi][ni] = __builtin_amdgcn_mfma_f32_16x16x32_bf16(af[mi], bfr[ni], acc[mi][ni], 0, 0, 0);
    }
  }

  const int r0 = g * 4;
#pragma unroll
  for (int mi = 0; mi < 4; ++mi) {
#pragma unroll
    for (int ni = 0; ni < 2; ++ni) {
      int mg = bm + wr * 64 + mi * 16 + r0;
      int ng = bn + wc * 32 + ni * 16 + cl;
#pragma unroll
      for (int r = 0; r < 4; ++r) {
        float v = acc[mi][ni][r] * escale;
        int m = mg + r;
        if (mode == 0) {
          ((float*)Cp)[(size_t)m * N + ng] = v;
        } else {
          int b = m >> 11, s = m & 2047;
          int h = ng >> 6, d = ng & 63;
          unsigned short* o = (unsigned short*)Cp;
          if (mode == 1) o[((size_t)(b * N_HEADS + h) * S_LEN + s) * 64 + d] = f2bf(v);
          else           o[((size_t)(b * N_HEADS + h) * 64 + d) * S_PAD + s] = f2bf(v);
        }
      }
    }
  }
}

// -- causal flash attention: LDS-staged shared K/V, 128q-row blocks -----------
// (unchanged from round 15)
__global__ __launch_bounds__(256) void attn_kernel(
    const unsigned short* __restrict__ Qg,
    const unsigned short* __restrict__ Kg,
    const unsigned short* __restrict__ Vtg,
    unsigned short* __restrict__ Og)
{
  __shared__ __align__(16) unsigned short Kb[2][8192];   // [buf][128 krow x 64 elem]
  __shared__ __align__(16) unsigned short Vb[2][8192];   // [buf][64 drow x 128 key]
  __shared__ __align__(16) unsigned short OB[4][32 * 72];

  const int tid = threadIdx.x;
  const int lane = tid & 63, wave = tid >> 6;
  const int l31 = lane & 31, hi = lane >> 5;

  const int bh = (blockIdx.x & 7) * 4 + ((blockIdx.x >> 3) & 3);
  const int p  = blockIdx.x >> 5;                  // pair 0..7
  const int tA = p, tB = 15 - p;                   // tiles of 128 q-rows
  const size_t qkb = (size_t)bh * S_LEN;
  const int b = bh >> 4, h = bh & 15;

  int cur = 0;

  auto stageK = [&](int buf, int ch) {
    const unsigned short* base = Kg + (qkb + (size_t)ch * 128) * 64;
#pragma unroll
    for (int ii = 0; ii < 4; ++ii) {
      int i = wave * 4 + ii;
      int ri = i * 8 + (lane >> 3);
      int e = (((lane & 7) ^ (lane >> 3)) << 3);
      gload16(base + (size_t)ri * 64 + e, &Kb[buf][i * 512]);
    }
  };
  auto stageV = [&](int buf, int ch) {
    const unsigned short* base = Vtg + (size_t)bh * 64 * S_PAD + ch * 128;
#pragma unroll
    for (int ii = 0; ii < 4; ++ii) {
      int i = wave * 4 + ii;
      int ri = i * 4 + (lane >> 4);
      int e = (((lane & 15) ^ (ri & 7)) << 3);
      gload16(base + (size_t)ri * S_PAD + e, &Vb[buf][i * 512]);
    }
  };

  const int swz = (l31 & 7) << 3;

  auto kblock = [&](int buf, const bf16x8 (&bq)[4], f32x16 (&o)[2], float& lpart,
                    int j, int jj, bool domask, int qrow) {
    bf16x8 kc[4];
    int krow = j * 32 + l31;
#pragma unroll
    for (int f = 0; f < 4; ++f)
      kc[f] = load8(&Kb[buf][krow * 64 + ((f * 16 + hi * 8) ^ swz)]);
    f32x16 c = {};
    __builtin_amdgcn_s_setprio(1);
#pragma unroll
    for (int f = 0; f < 4; ++f)
      c = __builtin_amdgcn_mfma_f32_32x32x16_bf16(kc[f], bq[f], c, 0, 0, 0);
    __builtin_amdgcn_s_setprio(0);
    if (domask) {
#pragma unroll
      for (int r = 0; r < 16; ++r) {
        int k = jj * 32 + (r & 3) + 8 * (r >> 2) + 4 * hi;
        if (k > qrow) c[r] = -1e30f;
      }
    }
    float s0 = 0.f, s1 = 0.f;
#pragma unroll
    for (int r = 0; r < 16; r += 2) {
      c[r] = __builtin_amdgcn_exp2f(c[r]);         s0 += c[r];
      c[r + 1] = __builtin_amdgcn_exp2f(c[r + 1]); s1 += c[r + 1];
    }
    lpart += s0 + s1;
    bf16x8 pb[2];
#pragma unroll
    for (int kf = 0; kf < 2; ++kf) {
      unsigned int x0 = cvtpk(c[8 * kf + 0], c[8 * kf + 1]);
      unsigned int x1 = cvtpk(c[8 * kf + 2], c[8 * kf + 3]);
      unsigned int y0 = cvtpk(c[8 * kf + 4], c[8 * kf + 5]);
      unsigned int y1 = cvtpk(c[8 * kf + 6], c[8 * kf + 7]);
      pl32swap(x0, y0); pl32swap(x1, y1);
      pb[kf] = __builtin_bit_cast(bf16x8, (uintx4){x0, x1, y0, y1});
    }
    bf16x8 vf[2][2];
#pragma unroll
    for (int kf = 0; kf < 2; ++kf)
#pragma unroll
      for (int dt = 0; dt < 2; ++dt)
        vf[kf][dt] = load8(&Vb[buf][(dt * 32 + l31) * 128 + ((j * 32 + kf * 16 + hi * 8) ^ swz)]);
    __builtin_amdgcn_s_setprio(1);
#pragma unroll
    for (int kf = 0; kf < 2; ++kf)
#pragma unroll
      for (int dt = 0; dt < 2; ++dt)
        o[dt] = __builtin_amdgcn_mfma_f32_32x32x16_bf16(vf[kf][dt], pb[kf], o[dt], 0, 0, 0);
    __builtin_amdgcn_s_setprio(0);
  };

  auto finalize = [&](int qt, f32x16 (&o)[2], float lpart) {
    float lf = lpart + __shfl_xor(lpart, 32, 64);
    float inv = 1.0f / lf;
    unsigned short* W = &OB[wave][0];
#pragma unroll
    for (int dt = 0; dt < 2; ++dt)
#pragma unroll
      for (int rc = 0; rc < 4; ++rc) {
        unsigned int u0 = cvtpk(o[dt][4 * rc] * inv, o[dt][4 * rc + 1] * inv);
        unsigned int u1 = cvtpk(o[dt][4 * rc + 2] * inv, o[dt][4 * rc + 3] * inv);
        unsigned long long pv = (unsigned long long)u0 | ((unsigned long long)u1 << 32);
        *(unsigned long long*)&W[l31 * 72 + dt * 32 + 8 * rc + 4 * hi] = pv;
      }
#pragma unroll
    for (int i = 0; i < 8; ++i) {
      int idx = i * 64 + lane;
      int qr = idx >> 4, c8 = idx & 15;
      unsigned long long v = *(const unsigned long long*)&W[qr * 72 + c8 * 4];
      *(unsigned long long*)&Og[((size_t)(b * S_LEN + qt + wave * 32 + qr)) * D_DIM + h * 64 + c8 * 4] = v;
    }
  };

  auto process_tile = [&](int t, int qt, bool stageNext) {
    bf16x8 bq[4];
#pragma unroll
    for (int f = 0; f < 4; ++f)
      bq[f] = load8(Qg + (qkb + qt + wave * 32 + l31) * 64 + f * 16 + hi * 8);
    f32x16 o[2] = {};
    float lpart = 0.f;

    for (int ch = 0; ch < t; ++ch) {
      stageK(cur ^ 1, ch + 1);
      stageV(cur ^ 1, ch + 1);
#pragma unroll
      for (int j = 0; j < 4; ++j)
        kblock(cur, bq, o, lpart, j, 0, false, 0);
      __syncthreads();
      cur ^= 1;
    }
    if (stageNext) { stageK(cur ^ 1, 0); stageV(cur ^ 1, 0); }
    int qrow = qt + wave * 32 + l31;
    for (int j = 0; j <= wave; ++j)
      kblock(cur, bq, o, lpart, j, 4 * t + j, j == wave, qrow);
    finalize(qt, o, lpart);
    __syncthreads();
    cur ^= 1;
  };

  stageK(0, 0); stageV(0, 0);
  __syncthreads();
  process_tile(tA, tA * 128, true);
  process_tile(tB, tB * 128, false);
}

extern "C" void kernel_launch(void* const* d_in, const int* in_sizes, int n_in,
                              void* d_out, int out_size, void* d_ws, size_t ws_size,
                              hipStream_t stream) {
  const float* x  = (const float*)d_in[0];
  const float* Wq = (const float*)d_in[1];
  const float* Wk = (const float*)d_in[2];
  const float* Wv = (const float*)d_in[3];
  const float* Wo = (const float*)d_in[4];

  const int M = M_ROWS, D = D_DIM;

  unsigned short* ws  = (unsigned short*)d_ws;
  unsigned short* xb  = ws;                          // M*D
  unsigned short* wqb = xb  + (size_t)M * D;         // D*D
  unsigned short* wkb = wqb + (size_t)D * D;
  unsigned short* wvb = wkb + (size_t)D * D;
  unsigned short* wob = wvb + (size_t)D * D;
  unsigned short* qb  = wob + (size_t)D * D;         // M*D  [B,H,S,64] (scaled)
  unsigned short* kbf = qb  + (size_t)M * D;         // M*D  [B,H,S,64]
  unsigned short* vtb = kbf + (size_t)M * D;         // 32*64*S_PAD [B,H,64,S_PAD]
  unsigned short* aob = vtb + (size_t)32 * 64 * S_PAD;  // M*D  [B,S,D]

  // 1) convert inputs to bf16 (single fused launch)
  {
    dim3 gc(M * D / 4 / 256, 5);
    cvt5_kernel<<<gc, 256, 0, stream>>>(x, Wq, Wk, Wv, Wo,
                                        xb, wqb, wkb, wvb, wob,
                                        M * D / 4, D * D / 4);
  }

  // 2) fused QKV projections (tile 128x64, 6 blocks/CU, XCD-affinity)
  dim3 gq(16, 32, 3);
  gemm_bt<<<gq, 256, 0, stream>>>(xb, wqb, wkb, wvb, qb, kbf, vtb, M, D, D, 1);

  // 3) causal flash attention (LDS-staged shared K/V, 256 uniform blocks)
  attn_kernel<<<256, 256, 0, stream>>>(qb, kbf, vtb, aob);

  // 4) output projection -> fp32 d_out (tile 128x64, 2 blocks/CU)
  dim3 go(16, 32, 1);
  gemm_bt<<<go, 256, 0, stream>>>(aob, wob, wob, wob, d_out, d_out, d_out, M, D, D, 0);
}

// Round 19
// 105.713 us; speedup vs baseline: 1.0569x; 1.0569x over previous
//
#include <hip/hip_runtime.h>
#include <hip/hip_bf16.h>

// Problem constants: B=2, S=2048, D=1024, H=16, dk=64
#define S_LEN 2048
#define S_PAD 2112
#define D_DIM 1024
#define N_HEADS 16
#define M_ROWS 4096  // B*S

typedef __bf16 bf16x8 __attribute__((ext_vector_type(8)));
typedef float f32x4 __attribute__((ext_vector_type(4)));
typedef float f32x16 __attribute__((ext_vector_type(16)));
typedef unsigned short ushortx8 __attribute__((ext_vector_type(8)));
typedef unsigned int uintx4 __attribute__((ext_vector_type(4)));

__device__ __forceinline__ unsigned short f2bf(float f) {
  unsigned int u = __builtin_bit_cast(unsigned int, f);
  u += 0x7fffu + ((u >> 16) & 1u);   // RNE
  return (unsigned short)(u >> 16);
}

// v_cvt_pk_bf16_f32: packs 2 f32 -> u32 (lo|hi<<16), RNE. No builtin on gfx950.
__device__ __forceinline__ unsigned int cvtpk(float lo, float hi) {
  unsigned int r;
  asm("v_cvt_pk_bf16_f32 %0, %1, %2" : "=v"(r) : "v"(lo), "v"(hi));
  return r;
}

// v_permlane32_swap_b32 a, b: a.lanes[32:63] <-> b.lanes[0:31]
__device__ __forceinline__ void pl32swap(unsigned int& a, unsigned int& b) {
  asm("v_permlane32_swap_b32 %0, %1" : "+v"(a), "+v"(b));
}

__device__ __forceinline__ bf16x8 load8(const unsigned short* p) {
  return __builtin_bit_cast(bf16x8, *(const ushortx8*)p);
}

__device__ __forceinline__ void gload16(const unsigned short* g, unsigned short* l) {
  __builtin_amdgcn_global_load_lds((const __attribute__((address_space(1))) void*)g,
                                   (__attribute__((address_space(3))) void*)l,
                                   16, 0, 0);
}

// ---------------- fp32 -> bf16 convert (fused: x + 4 weights) ----------------
__global__ void cvt5_kernel(const float* __restrict__ s0, const float* __restrict__ s1,
                            const float* __restrict__ s2, const float* __restrict__ s3,
                            const float* __restrict__ s4,
                            unsigned short* __restrict__ d0, unsigned short* __restrict__ d1,
                            unsigned short* __restrict__ d2, unsigned short* __restrict__ d3,
                            unsigned short* __restrict__ d4,
                            int n4x, int n4w) {
  const int y = blockIdx.y;
  const float* s = (y == 0) ? s0 : (y == 1) ? s1 : (y == 2) ? s2 : (y == 3) ? s3 : s4;
  unsigned short* d = (y == 0) ? d0 : (y == 1) ? d1 : (y == 2) ? d2 : (y == 3) ? d3 : d4;
  const int n4 = (y == 0) ? n4x : n4w;
  int i = blockIdx.x * blockDim.x + threadIdx.x;
  if (i < n4) {
    float4 f = ((const float4*)s)[i];
    unsigned int u0 = cvtpk(f.x, f.y), u1 = cvtpk(f.z, f.w);
    unsigned long long packed = (unsigned long long)u0 | ((unsigned long long)u1 << 32);
    ((unsigned long long*)d)[i] = packed;
  }
}

// ---------------- bf16 GEMM (QKV): C = A[M,K] * B[N,K]^T, tile 128x128 -------
// R17 config (proven 55us): XCD-affinity remap, gridDim == (8,32,3).
// mode 1: bf16 [B,H,S,64] (Q pre-scaled log2e/8); mode 2: bf16 [B,H,64,S_PAD].
__global__ __launch_bounds__(256) void gemm_bt(
    const unsigned short* __restrict__ A,
    const unsigned short* __restrict__ B0,
    const unsigned short* __restrict__ B1,
    const unsigned short* __restrict__ B2,
    void* __restrict__ C0, void* __restrict__ C1, void* __restrict__ C2,
    int M, int N, int K, int modesel)
{
  __shared__ __align__(16) unsigned short At[128 * 64];
  __shared__ __align__(16) unsigned short Bt[128 * 64];

  // XCD-affinity remap: bid%8 = XCD; within XCD, x fastest, then y, z slowest.
  const int bid = blockIdx.x + 8 * (blockIdx.y + 32 * blockIdx.z);
  const int k8 = bid & 7, t = bid >> 3;
  const int zz = t >> 5;
  const int u = t & 31;
  const int bxi = (k8 & 1) * 4 + (u & 3);
  const int byi = (k8 >> 1) * 8 + (u >> 2);

  const int z = zz;
  const unsigned short* Bp = (z == 0) ? B0 : (z == 1) ? B1 : B2;
  void* Cp = (z == 0) ? C0 : (z == 1) ? C1 : C2;
  const int mode = (modesel == 0) ? 0 : ((z == 2) ? 2 : 1);
  const float escale = (modesel == 1 && z == 0) ? 0.180336879f : 1.0f;

  const int tid = threadIdx.x;
  const int lane = tid & 63, wave = tid >> 6;
  const int bm = byi * 128, bn = bxi * 128;
  const int wr = wave >> 1, wc = wave & 1;
  const int cl = lane & 15, g = lane >> 4;
  const int ci = lane >> 3, si = lane & 7;
  const int sg = si ^ (ci & 7);

  f32x4 acc[4][4] = {};

  for (int kb = 0; kb < K; kb += 64) {
    __syncthreads();
#pragma unroll
    for (int cc = 0; cc < 4; ++cc) {
      int chunk = wave * 4 + cc;
      int row = chunk * 8 + ci;
      gload16(A  + (size_t)(bm + row) * K + kb + sg * 8, &At[chunk * 512]);
      gload16(Bp + (size_t)(bn + row) * K + kb + sg * 8, &Bt[chunk * 512]);
    }
    __syncthreads();
#pragma unroll
    for (int kc = 0; kc < 2; ++kc) {
      bf16x8 af[4], bfr[4];
#pragma unroll
      for (int mi = 0; mi < 4; ++mi) {
        int row = wr * 64 + mi * 16 + cl;
        int slot = (kc * 4 + g) ^ (row & 7);
        af[mi] = load8(&At[row * 64 + slot * 8]);
      }
#pragma unroll
      for (int ni = 0; ni < 4; ++ni) {
        int row = wc * 64 + ni * 16 + cl;
        int slot = (kc * 4 + g) ^ (row & 7);
        bfr[ni] = load8(&Bt[row * 64 + slot * 8]);
      }
#pragma unroll
      for (int mi = 0; mi < 4; ++mi)
#pragma unroll
        for (int ni = 0; ni < 4; ++ni)
          acc[mi][ni] = __builtin_amdgcn_mfma_f32_16x16x32_bf16(af[mi], bfr[ni], acc[mi][ni], 0, 0, 0);
    }
  }

  const int r0 = g * 4;
#pragma unroll
  for (int mi = 0; mi < 4; ++mi) {
#pragma unroll
    for (int ni = 0; ni < 4; ++ni) {
      int mg = bm + wr * 64 + mi * 16 + r0;
      int ng = bn + wc * 64 + ni * 16 + cl;
#pragma unroll
      for (int r = 0; r < 4; ++r) {
        float v = acc[mi][ni][r] * escale;
        int m = mg + r;
        if (mode == 0) {
          ((float*)Cp)[(size_t)m * N + ng] = v;
        } else {
          int b = m >> 11, s = m & 2047;
          int h = ng >> 6, d = ng & 63;
          unsigned short* o = (unsigned short*)Cp;
          if (mode == 1) o[((size_t)(b * N_HEADS + h) * S_LEN + s) * 64 + d] = f2bf(v);
          else           o[((size_t)(b * N_HEADS + h) * 64 + d) * S_PAD + s] = f2bf(v);
        }
      }
    }
  }
}

// ---------------- output projection GEMM: tile 64M x 128N, fp32 out ---------
// Dedicated kernel: 512 blocks = 2 blocks/CU (the 128x128 version gave only
// 1/CU = pure drain regime). LDS 24KB, acc[2][4] (~40 VGPR).
// XCD-affinity: XCD k owns m-tiles [8k, 8k+8) (A-slab 1MB) x all n (B 2MB);
// n fastest within XCD for A-panel back-to-back reuse.
__global__ __launch_bounds__(256) void gemm_o64(
    const unsigned short* __restrict__ A,
    const unsigned short* __restrict__ B,
    float* __restrict__ C, int M, int N, int K)
{
  __shared__ __align__(16) unsigned short At[64 * 64];    // 8KB
  __shared__ __align__(16) unsigned short Bt[128 * 64];   // 16KB

  const int bid = blockIdx.x;
  const int k8 = bid & 7, t = bid >> 3;
  const int bxi = t & 7;               // 8 n-tiles of 128
  const int byi = k8 * 8 + (t >> 3);   // 64 m-tiles of 64

  const int tid = threadIdx.x;
  const int lane = tid & 63, wave = tid >> 6;
  const int bm = byi * 64, bn = bxi * 128;
  const int wr = wave >> 1, wc = wave & 1;   // wave owns 32M x 64N
  const int cl = lane & 15, g = lane >> 4;
  const int ci = lane >> 3, si = lane & 7;
  const int sg = si ^ (ci & 7);

  f32x4 acc[2][4] = {};

  for (int kb = 0; kb < K; kb += 64) {
    __syncthreads();
#pragma unroll
    for (int cc = 0; cc < 2; ++cc) {           // A: 8 chunks of 512
      int chunk = wave * 2 + cc;
      int row = chunk * 8 + ci;
      gload16(A + (size_t)(bm + row) * K + kb + sg * 8, &At[chunk * 512]);
    }
#pragma unroll
    for (int cc = 0; cc < 4; ++cc) {           // B: 16 chunks of 512
      int chunk = wave * 4 + cc;
      int row = chunk * 8 + ci;
      gload16(B + (size_t)(bn + row) * K + kb + sg * 8, &Bt[chunk * 512]);
    }
    __syncthreads();
#pragma unroll
    for (int kc = 0; kc < 2; ++kc) {
      bf16x8 af[2], bfr[4];
#pragma unroll
      for (int mi = 0; mi < 2; ++mi) {
        int row = wr * 32 + mi * 16 + cl;
        int slot = (kc * 4 + g) ^ (row & 7);
        af[mi] = load8(&At[row * 64 + slot * 8]);
      }
#pragma unroll
      for (int ni = 0; ni < 4; ++ni) {
        int row = wc * 64 + ni * 16 + cl;
        int slot = (kc * 4 + g) ^ (row & 7);
        bfr[ni] = load8(&Bt[row * 64 + slot * 8]);
      }
#pragma unroll
      for (int mi = 0; mi < 2; ++mi)
#pragma unroll
        for (int ni = 0; ni < 4; ++ni)
          acc[mi][ni] = __builtin_amdgcn_mfma_f32_16x16x32_bf16(af[mi], bfr[ni], acc[mi][ni], 0, 0, 0);
    }
  }

  const int r0 = g * 4;
#pragma unroll
  for (int mi = 0; mi < 2; ++mi)
#pragma unroll
    for (int ni = 0; ni < 4; ++ni) {
      int mg = bm + wr * 32 + mi * 16 + r0;
      int ng = bn + wc * 64 + ni * 16 + cl;
#pragma unroll
      for (int r = 0; r < 4; ++r)
        C[(size_t)(mg + r) * N + ng] = acc[mi][ni][r];
    }
}

// -- causal flash attention: LDS-staged shared K/V, 128q-row blocks -----------
// (unchanged from round 15)
__global__ __launch_bounds__(256) void attn_kernel(
    const unsigned short* __restrict__ Qg,
    const unsigned short* __restrict__ Kg,
    const unsigned short* __restrict__ Vtg,
    unsigned short* __restrict__ Og)
{
  __shared__ __align__(16) unsigned short Kb[2][8192];   // [buf][128 krow x 64 elem]
  __shared__ __align__(16) unsigned short Vb[2][8192];   // [buf][64 drow x 128 key]
  __shared__ __align__(16) unsigned short OB[4][32 * 72];

  const int tid = threadIdx.x;
  const int lane = tid & 63, wave = tid >> 6;
  const int l31 = lane & 31, hi = lane >> 5;

  const int bh = (blockIdx.x & 7) * 4 + ((blockIdx.x >> 3) & 3);
  const int p  = blockIdx.x >> 5;                  // pair 0..7
  const int tA = p, tB = 15 - p;                   // tiles of 128 q-rows
  const size_t qkb = (size_t)bh * S_LEN;
  const int b = bh >> 4, h = bh & 15;

  int cur = 0;

  auto stageK = [&](int buf, int ch) {
    const unsigned short* base = Kg + (qkb + (size_t)ch * 128) * 64;
#pragma unroll
    for (int ii = 0; ii < 4; ++ii) {
      int i = wave * 4 + ii;
      int ri = i * 8 + (lane >> 3);
      int e = (((lane & 7) ^ (lane >> 3)) << 3);
      gload16(base + (size_t)ri * 64 + e, &Kb[buf][i * 512]);
    }
  };
  auto stageV = [&](int buf, int ch) {
    const unsigned short* base = Vtg + (size_t)bh * 64 * S_PAD + ch * 128;
#pragma unroll
    for (int ii = 0; ii < 4; ++ii) {
      int i = wave * 4 + ii;
      int ri = i * 4 + (lane >> 4);
      int e = (((lane & 15) ^ (ri & 7)) << 3);
      gload16(base + (size_t)ri * S_PAD + e, &Vb[buf][i * 512]);
    }
  };

  const int swz = (l31 & 7) << 3;

  auto kblock = [&](int buf, const bf16x8 (&bq)[4], f32x16 (&o)[2], float& lpart,
                    int j, int jj, bool domask, int qrow) {
    bf16x8 kc[4];
    int krow = j * 32 + l31;
#pragma unroll
    for (int f = 0; f < 4; ++f)
      kc[f] = load8(&Kb[buf][krow * 64 + ((f * 16 + hi * 8) ^ swz)]);
    f32x16 c = {};
    __builtin_amdgcn_s_setprio(1);
#pragma unroll
    for (int f = 0; f < 4; ++f)
      c = __builtin_amdgcn_mfma_f32_32x32x16_bf16(kc[f], bq[f], c, 0, 0, 0);
    __builtin_amdgcn_s_setprio(0);
    if (domask) {
#pragma unroll
      for (int r = 0; r < 16; ++r) {
        int k = jj * 32 + (r & 3) + 8 * (r >> 2) + 4 * hi;
        if (k > qrow) c[r] = -1e30f;
      }
    }
    float s0 = 0.f, s1 = 0.f;
#pragma unroll
    for (int r = 0; r < 16; r += 2) {
      c[r] = __builtin_amdgcn_exp2f(c[r]);         s0 += c[r];
      c[r + 1] = __builtin_amdgcn_exp2f(c[r + 1]); s1 += c[r + 1];
    }
    lpart += s0 + s1;
    bf16x8 pb[2];
#pragma unroll
    for (int kf = 0; kf < 2; ++kf) {
      unsigned int x0 = cvtpk(c[8 * kf + 0], c[8 * kf + 1]);
      unsigned int x1 = cvtpk(c[8 * kf + 2], c[8 * kf + 3]);
      unsigned int y0 = cvtpk(c[8 * kf + 4], c[8 * kf + 5]);
      unsigned int y1 = cvtpk(c[8 * kf + 6], c[8 * kf + 7]);
      pl32swap(x0, y0); pl32swap(x1, y1);
      pb[kf] = __builtin_bit_cast(bf16x8, (uintx4){x0, x1, y0, y1});
    }
    bf16x8 vf[2][2];
#pragma unroll
    for (int kf = 0; kf < 2; ++kf)
#pragma unroll
      for (int dt = 0; dt < 2; ++dt)
        vf[kf][dt] = load8(&Vb[buf][(dt * 32 + l31) * 128 + ((j * 32 + kf * 16 + hi * 8) ^ swz)]);
    __builtin_amdgcn_s_setprio(1);
#pragma unroll
    for (int kf = 0; kf < 2; ++kf)
#pragma unroll
      for (int dt = 0; dt < 2; ++dt)
        o[dt] = __builtin_amdgcn_mfma_f32_32x32x16_bf16(vf[kf][dt], pb[kf], o[dt], 0, 0, 0);
    __builtin_amdgcn_s_setprio(0);
  };

  auto finalize = [&](int qt, f32x16 (&o)[2], float lpart) {
    float lf = lpart + __shfl_xor(lpart, 32, 64);
    float inv = 1.0f / lf;
    unsigned short* W = &OB[wave][0];
#pragma unroll
    for (int dt = 0; dt < 2; ++dt)
#pragma unroll
      for (int rc = 0; rc < 4; ++rc) {
        unsigned int u0 = cvtpk(o[dt][4 * rc] * inv, o[dt][4 * rc + 1] * inv);
        unsigned int u1 = cvtpk(o[dt][4 * rc + 2] * inv, o[dt][4 * rc + 3] * inv);
        unsigned long long pv = (unsigned long long)u0 | ((unsigned long long)u1 << 32);
        *(unsigned long long*)&W[l31 * 72 + dt * 32 + 8 * rc + 4 * hi] = pv;
      }
#pragma unroll
    for (int i = 0; i < 8; ++i) {
      int idx = i * 64 + lane;
      int qr = idx >> 4, c8 = idx & 15;
      unsigned long long v = *(const unsigned long long*)&W[qr * 72 + c8 * 4];
      *(unsigned long long*)&Og[((size_t)(b * S_LEN + qt + wave * 32 + qr)) * D_DIM + h * 64 + c8 * 4] = v;
    }
  };

  auto process_tile = [&](int t, int qt, bool stageNext) {
    bf16x8 bq[4];
#pragma unroll
    for (int f = 0; f < 4; ++f)
      bq[f] = load8(Qg + (qkb + qt + wave * 32 + l31) * 64 + f * 16 + hi * 8);
    f32x16 o[2] = {};
    float lpart = 0.f;

    for (int ch = 0; ch < t; ++ch) {
      stageK(cur ^ 1, ch + 1);
      stageV(cur ^ 1, ch + 1);
#pragma unroll
      for (int j = 0; j < 4; ++j)
        kblock(cur, bq, o, lpart, j, 0, false, 0);
      __syncthreads();
      cur ^= 1;
    }
    if (stageNext) { stageK(cur ^ 1, 0); stageV(cur ^ 1, 0); }
    int qrow = qt + wave * 32 + l31;
    for (int j = 0; j <= wave; ++j)
      kblock(cur, bq, o, lpart, j, 4 * t + j, j == wave, qrow);
    finalize(qt, o, lpart);
    __syncthreads();
    cur ^= 1;
  };

  stageK(0, 0); stageV(0, 0);
  __syncthreads();
  process_tile(tA, tA * 128, true);
  process_tile(tB, tB * 128, false);
}

extern "C" void kernel_launch(void* const* d_in, const int* in_sizes, int n_in,
                              void* d_out, int out_size, void* d_ws, size_t ws_size,
                              hipStream_t stream) {
  const float* x  = (const float*)d_in[0];
  const float* Wq = (const float*)d_in[1];
  const float* Wk = (const float*)d_in[2];
  const float* Wv = (const float*)d_in[3];
  const float* Wo = (const float*)d_in[4];

  const int M = M_ROWS, D = D_DIM;

  unsigned short* ws  = (unsigned short*)d_ws;
  unsigned short* xb  = ws;                          // M*D
  unsigned short* wqb = xb  + (size_t)M * D;         // D*D
  unsigned short* wkb = wqb + (size_t)D * D;
  unsigned short* wvb = wkb + (size_t)D * D;
  unsigned short* wob = wvb + (size_t)D * D;
  unsigned short* qb  = wob + (size_t)D * D;         // M*D  [B,H,S,64] (scaled)
  unsigned short* kbf = qb  + (size_t)M * D;         // M*D  [B,H,S,64]
  unsigned short* vtb = kbf + (size_t)M * D;         // 32*64*S_PAD [B,H,64,S_PAD]
  unsigned short* aob = vtb + (size_t)32 * 64 * S_PAD;  // M*D  [B,S,D]

  // 1) convert inputs to bf16 (single fused launch)
  {
    dim3 gc(M * D / 4 / 256, 5);
    cvt5_kernel<<<gc, 256, 0, stream>>>(x, Wq, Wk, Wv, Wo,
                                        xb, wqb, wkb, wvb, wob,
                                        M * D / 4, D * D / 4);
  }

  // 2) fused QKV projections (128x128 tile, XCD-affinity — R17 config)
  dim3 gq(8, 32, 3);
  gemm_bt<<<gq, 256, 0, stream>>>(xb, wqb, wkb, wvb, qb, kbf, vtb, M, D, D, 1);

  // 3) causal flash attention (LDS-staged shared K/V, 256 uniform blocks)
  attn_kernel<<<256, 256, 0, stream>>>(qb, kbf, vtb, aob);

  // 4) output projection -> fp32 d_out (64x128 tile, 512 blocks = 2/CU)
  gemm_o64<<<512, 256, 0, stream>>>(aob, wob, (float*)d_out, M, D, D);
}